// Round 4
// baseline (207.364 us; speedup 1.0000x reference)
//
#include <hip/hip_runtime.h>
#include <stdint.h>

// GraphConvolution: out = relu(x@W1^T + b1 + aggr@W2^T + b2), aggr = sum of 16 neighbor rows.
// Folded into one bf16 GEMM: [x|aggr](100000x256) @ [W1;W2]^T(256x128) + (b1+b2), relu.
// R4: FUSED aggr+GEMM. Per 128-row block: stage x-tile (gload_lds) -> gather neighbors into
// swizzled LDS aggr buffer (never hits global) -> 4 BK=64 MFMA K-steps (x from LDS, aggr from
// LDS, W direct-from-global L2-hot) -> bias+relu epilogue. Removes aggr 25.6MB write + 25.6MB
// re-read + one launch; gather overlaps MFMA across 3 resident blocks/CU.

#define N_NODES 100000
#define DEG 16
#define M_PAD 100096  // 782 * 128

typedef __attribute__((ext_vector_type(8))) short short8;
typedef __attribute__((ext_vector_type(4))) float floatx4;

static __device__ __forceinline__ unsigned short f2bf(float f) {
  union { float f; uint32_t u; } v; v.f = f;
  uint32_t u = v.u;
  return (unsigned short)((u + 0x7fffu + ((u >> 16) & 1u)) >> 16);  // RNE
}
static __device__ __forceinline__ float bf2f(uint32_t bits16) {
  union { uint32_t u; float f; } v; v.u = bits16 << 16; return v.f;
}

// ---- kernel 1: x fp32 -> bf16 dense Xb[M_PAD][128]  +  W/bias prep (merged) ----
__global__ __launch_bounds__(256) void k_convert(const float* __restrict__ x,
                                                 unsigned short* __restrict__ Xb,
                                                 const float* __restrict__ W1, const float* __restrict__ b1,
                                                 const float* __restrict__ W2, const float* __restrict__ b2,
                                                 unsigned short* __restrict__ Bt, float* __restrict__ bias) {
  int b = blockIdx.x;
  if (b < 12500) {                      // 12500*256 threads == N*32 float4 chunks exactly
    int t = b * 256 + threadIdx.x;
    int n = t >> 5, c4 = t & 31;
    float4 v = *(const float4*)(x + (size_t)n * 128 + (size_t)c4 * 4);
    ushort4 o;
    o.x = f2bf(v.x); o.y = f2bf(v.y); o.z = f2bf(v.z); o.w = f2bf(v.w);
    *(ushort4*)(Xb + (size_t)n * 128 + (size_t)c4 * 4) = o;
  } else {                              // Bt row o = [W1[o,:], W2[o,:]] bf16; bias = b1+b2
    int t = (b - 12500) * 256 + threadIdx.x;  // 0..32767
    int o = t >> 8, k = t & 255;
    float v = (k < 128) ? W1[o * 128 + k] : W2[o * 128 + (k - 128)];
    Bt[t] = f2bf(v);
    if (t < 128) bias[t] = b1[t] + b2[t];
  }
}

// ---- kernel 2: fused gather-aggregate + GEMM ----
// 256 threads = 4 waves (2x2 of 64x64 output). LDS: aggr 32KB [128 rows][16 slots16B,
// slot^=(row&7)] + xbuf 16KB [128 rows][8 slots16B, slot^=(row&7)]. 48KB -> 3 blocks/CU.
__global__ __launch_bounds__(256, 3) void k_fused(const int* __restrict__ nbrs,
                                                  const unsigned short* __restrict__ Xb,
                                                  const unsigned short* __restrict__ Bt,
                                                  const float* __restrict__ bias,
                                                  float* __restrict__ out) {
  __shared__ uint4 smem4[3072];  // 48KB
  char* aggr = (char*)smem4;         // 32KB
  char* xbuf = (char*)smem4 + 32768; // 16KB
  const int tid = threadIdx.x;
  const int lane = tid & 63;
  const int w = tid >> 6;
  const int wm = w >> 1, wn = w & 1;
  const int q16 = lane >> 4, c16 = lane & 15;
  const size_t tile = (size_t)blockIdx.x * 128;
  const char* Xbb = (const char*)Xb;  // rows 256B
  const char* Btb = (const char*)Bt;  // rows 512B

  float bcol[4];
#pragma unroll
  for (int ni = 0; ni < 4; ++ni) bcol[ni] = bias[wn * 64 + ni * 16 + (lane & 15)];

  // stage x-tile K-chunk kt (64 cols = 128B/row) into xbuf; source pre-swizzled so that
  // linear LDS slot p of row r holds logical slot p^(r&7)  (2-way bank spread on read).
  auto STAGE = [&](int kt) {
    int g = ((lane & 7) ^ (lane >> 3)) * 16;
#pragma unroll
    for (int s = 0; s < 4; ++s) {
      int br = w * 32 + s * 8;  // 8 rows / 1KB per instr
      const char* src = Xbb + (tile + br + (lane >> 3)) * 256 + kt * 128 + g;
      __builtin_amdgcn_global_load_lds((const __attribute__((address_space(1))) uint32_t*)src,
                                       (__attribute__((address_space(3))) uint32_t*)(xbuf + br * 128),
                                       16, 0, 0);
    }
  };

  STAGE(0);  // issue first — its latency hides under the whole gather phase

  // ---- gather: each wave aggregates its 32 rows; dwordx4 = 4 neighbor rows / instr ----
  for (int r = 0; r < 8; ++r) {
    int nodeb = (int)tile + w * 32 + r * 4;
    int gi = nodeb * 16 + lane;  // 4 nodes' index lists
    int midx = (gi < N_NODES * DEG) ? nbrs[gi] : 0;
#pragma unroll
    for (int q = 0; q < 4; ++q) {
      int row = w * 32 + r * 4 + q;
      float a8[8] = {0.f, 0.f, 0.f, 0.f, 0.f, 0.f, 0.f, 0.f};
#pragma unroll
      for (int i = 0; i < 4; ++i) {
        int nb = __shfl(midx, q * 16 + i * 4 + q16);
        uint4 pv = *(const uint4*)(Xbb + (size_t)nb * 256 + c16 * 16);
        a8[0] += bf2f(pv.x & 0xffffu); a8[1] += bf2f(pv.x >> 16);
        a8[2] += bf2f(pv.y & 0xffffu); a8[3] += bf2f(pv.y >> 16);
        a8[4] += bf2f(pv.z & 0xffffu); a8[5] += bf2f(pv.z >> 16);
        a8[6] += bf2f(pv.w & 0xffffu); a8[7] += bf2f(pv.w >> 16);
      }
#pragma unroll
      for (int k = 0; k < 8; ++k) {
        a8[k] += __shfl_xor(a8[k], 16);
        a8[k] += __shfl_xor(a8[k], 32);
      }
      if (lane < 16) {
        bool valid = (tile + row) < N_NODES;
        uint4 wv;
        wv.x = valid ? ((uint32_t)f2bf(a8[0]) | ((uint32_t)f2bf(a8[1]) << 16)) : 0u;
        wv.y = valid ? ((uint32_t)f2bf(a8[2]) | ((uint32_t)f2bf(a8[3]) << 16)) : 0u;
        wv.z = valid ? ((uint32_t)f2bf(a8[4]) | ((uint32_t)f2bf(a8[5]) << 16)) : 0u;
        wv.w = valid ? ((uint32_t)f2bf(a8[6]) | ((uint32_t)f2bf(a8[7]) << 16)) : 0u;
        *(uint4*)(aggr + row * 256 + ((c16 ^ (row & 7)) * 16)) = wv;
      }
    }
  }

  floatx4 acc[4][4];
#pragma unroll
  for (int i = 0; i < 4; ++i)
#pragma unroll
    for (int j = 0; j < 4; ++j) acc[i][j] = (floatx4){0.f, 0.f, 0.f, 0.f};

  // one BK=64 K-step: A-frags from LDS (xbuf or aggr), B-frags direct from global (L2-hot 64KB)
  auto COMP = [&](int kt, int from_aggr) {
#pragma unroll
    for (int ks = 0; ks < 2; ++ks) {
      short8 a[4], b[4];
#pragma unroll
      for (int mi = 0; mi < 4; ++mi) {
        int row = wm * 64 + mi * 16 + (lane & 15);  // row&7 == lane&7
        if (from_aggr) {
          int slot = (kt - 2) * 8 + ks * 4 + q16;
          a[mi] = *(const short8*)(aggr + row * 256 + ((slot ^ (lane & 7)) * 16));
        } else {
          int k8 = ks * 4 + q16;
          a[mi] = *(const short8*)(xbuf + row * 128 + ((k8 ^ (lane & 7)) * 16));
        }
      }
#pragma unroll
      for (int ni = 0; ni < 4; ++ni) {
        int o = wn * 64 + ni * 16 + (lane & 15);
        int slot = kt * 8 + ks * 4 + q16;
        b[ni] = *(const short8*)(Btb + (size_t)o * 512 + slot * 16);
      }
      __builtin_amdgcn_s_setprio(1);
#pragma unroll
      for (int mi = 0; mi < 4; ++mi)
#pragma unroll
        for (int ni = 0; ni < 4; ++ni)
          acc[mi][ni] = __builtin_amdgcn_mfma_f32_16x16x32_bf16(a[mi], b[ni], acc[mi][ni], 0, 0, 0);
      __builtin_amdgcn_s_setprio(0);
    }
  };

  __syncthreads();     // aggr LDS visible + STAGE(0) landed (drains vmcnt+lgkmcnt)
  COMP(0, 0);          // x cols 0-63
  __syncthreads();     // all waves done reading xbuf kt0
  STAGE(1);            // restage xbuf with x cols 64-127
  COMP(2, 1);          // aggr cols 0-63 — covers STAGE(1) latency
  __syncthreads();     // STAGE(1) landed
  COMP(1, 0);          // x cols 64-127
  COMP(3, 1);          // aggr cols 64-127

  // epilogue: C/D layout col=lane&15, row=(lane>>4)*4+reg (m89-verified)
  const int r0 = (lane >> 4) * 4;
#pragma unroll
  for (int mi = 0; mi < 4; ++mi) {
    size_t mbase = tile + wm * 64 + mi * 16 + r0;
#pragma unroll
    for (int r = 0; r < 4; ++r) {
      size_t mrow = mbase + r;
      if (mrow < N_NODES) {
        float* orow = out + mrow * 128 + wn * 64 + (lane & 15);
#pragma unroll
        for (int ni = 0; ni < 4; ++ni) {
          float vv = acc[mi][ni][r] + bcol[ni];
          orow[ni * 16] = vv > 0.f ? vv : 0.f;
        }
      }
    }
  }
}

extern "C" void kernel_launch(void* const* d_in, const int* in_sizes, int n_in,
                              void* d_out, int out_size, void* d_ws, size_t ws_size,
                              hipStream_t stream) {
  const int* nbrs  = (const int*)d_in[0];
  const float* x   = (const float*)d_in[1];
  const float* W1  = (const float*)d_in[2];
  const float* b1  = (const float*)d_in[3];
  const float* W2  = (const float*)d_in[4];
  const float* b2  = (const float*)d_in[5];
  float* out = (float*)d_out;

  // ws layout: Xb bf16 [M_PAD][128] | Bt bf16 [128][256] | bias f32 [128]
  unsigned short* Xb = (unsigned short*)d_ws;
  unsigned short* Bt = Xb + (size_t)M_PAD * 128;
  float* bias = (float*)(Bt + 128 * 256);

  k_convert<<<12628, 256, 0, stream>>>(x, Xb, W1, b1, W2, b2, Bt, bias);
  k_fused<<<782, 256, 0, stream>>>(nbrs, Xb, Bt, bias, out);
}

// Round 5
// 177.853 us; speedup vs baseline: 1.1659x; 1.1659x over previous
//
#include <hip/hip_runtime.h>
#include <stdint.h>

// GraphConvolution: out = relu(x@W1^T + b1 + aggr@W2^T + b2), aggr = sum of 16 neighbor rows.
// R5: fused gather+GEMM at M-tile=32 (3125 blocks) to keep gather occupancy high (R4 post-
// mortem: 782-block fusion was grid-starved, occupancy 20%, gather BW collapsed). Per block:
// 4 waves gather 8 nodes each into 8KB swizzled LDS; x/W fragments read direct from global;
// each wave computes a 32x32 output quadrant; bias+relu epilogue. No aggr global round-trip.

#define N_NODES 100000
#define DEG 16

typedef __attribute__((ext_vector_type(8))) short short8;
typedef __attribute__((ext_vector_type(4))) float floatx4;

static __device__ __forceinline__ unsigned short f2bf(float f) {
  union { float f; uint32_t u; } v; v.f = f;
  uint32_t u = v.u;
  return (unsigned short)((u + 0x7fffu + ((u >> 16) & 1u)) >> 16);  // RNE
}
static __device__ __forceinline__ float bf2f(uint32_t bits16) {
  union { uint32_t u; float f; } v; v.u = bits16 << 16; return v.f;
}

// ---- kernel 1: x fp32 -> bf16 Xb[100000][128]  +  W/bias prep (merged) ----
__global__ __launch_bounds__(256) void k_convert(const float* __restrict__ x,
                                                 unsigned short* __restrict__ Xb,
                                                 const float* __restrict__ W1, const float* __restrict__ b1,
                                                 const float* __restrict__ W2, const float* __restrict__ b2,
                                                 unsigned short* __restrict__ Bt, float* __restrict__ bias) {
  int b = blockIdx.x;
  if (b < 12500) {                      // 12500*256 threads == N*32 float4 chunks exactly
    int t = b * 256 + threadIdx.x;
    int n = t >> 5, c4 = t & 31;
    float4 v = *(const float4*)(x + (size_t)n * 128 + (size_t)c4 * 4);
    ushort4 o;
    o.x = f2bf(v.x); o.y = f2bf(v.y); o.z = f2bf(v.z); o.w = f2bf(v.w);
    *(ushort4*)(Xb + (size_t)n * 128 + (size_t)c4 * 4) = o;
  } else {                              // Bt row o = [W1[o,:], W2[o,:]] bf16; bias = b1+b2
    int t = (b - 12500) * 256 + threadIdx.x;  // 0..32767
    int o = t >> 8, k = t & 255;
    float v = (k < 128) ? W1[o * 128 + k] : W2[o * 128 + (k - 128)];
    Bt[t] = f2bf(v);
    if (t < 128) bias[t] = b1[t] + b2[t];
  }
}

// ---- kernel 2: fused gather + GEMM, tile = 32 rows, 4 waves ----
// LDS: aggr only, 32 rows x 256B = 8KB, 16B slots, slot ^= (row&7) (2-way free).
// Wave w: gathers nodes [tile+8w, +8); computes output quadrant cols [32w, 32w+32).
__global__ __launch_bounds__(256, 8) void k_fused(const int* __restrict__ nbrs,
                                                  const unsigned short* __restrict__ Xb,
                                                  const unsigned short* __restrict__ Bt,
                                                  const float* __restrict__ bias,
                                                  float* __restrict__ out) {
  __shared__ uint4 aggr4[512];  // 8KB
  char* aggr = (char*)aggr4;
  const int tid = threadIdx.x;
  const int lane = tid & 63;
  const int w = tid >> 6;
  const int q16 = lane >> 4, c16 = lane & 15;
  const int tile = blockIdx.x * 32;  // 3125*32 = 100000 exactly, no padding
  const char* Xbb = (const char*)Xb;  // 256B rows
  const char* Btb = (const char*)Bt;  // 512B rows

  // bias early (off critical path)
  float bcol[2];
#pragma unroll
  for (int ni = 0; ni < 2; ++ni) bcol[ni] = bias[w * 32 + ni * 16 + c16];

  // this wave's 8 nodes' neighbour indices: 128 ints, coalesced
  int base = (tile + w * 8) * DEG;
  int midx0 = nbrs[base + lane];        // nodes q=0..3 (index j of node q at lane q*16+j)
  int midx1 = nbrs[base + 64 + lane];   // nodes q=4..7

  // ---- gather: node q -> LDS row w*8+q (dwordx4: 4 neighbor rows / instr) ----
  for (int q = 0; q < 8; ++q) {
    int midx = (q < 4) ? midx0 : midx1;
    int flat = (q & 3) * 16 + q16;
    float a8[8] = {0.f, 0.f, 0.f, 0.f, 0.f, 0.f, 0.f, 0.f};
#pragma unroll
    for (int i = 0; i < 4; ++i) {
      int nb = __shfl(midx, flat + i * 4);
      uint4 pv = *(const uint4*)(Xbb + (size_t)nb * 256 + c16 * 16);
      a8[0] += bf2f(pv.x & 0xffffu); a8[1] += bf2f(pv.x >> 16);
      a8[2] += bf2f(pv.y & 0xffffu); a8[3] += bf2f(pv.y >> 16);
      a8[4] += bf2f(pv.z & 0xffffu); a8[5] += bf2f(pv.z >> 16);
      a8[6] += bf2f(pv.w & 0xffffu); a8[7] += bf2f(pv.w >> 16);
    }
#pragma unroll
    for (int k = 0; k < 8; ++k) {
      a8[k] += __shfl_xor(a8[k], 16);
      a8[k] += __shfl_xor(a8[k], 32);
    }
    if (lane < 16) {
      int row = w * 8 + q;
      uint4 wv;
      wv.x = (uint32_t)f2bf(a8[0]) | ((uint32_t)f2bf(a8[1]) << 16);
      wv.y = (uint32_t)f2bf(a8[2]) | ((uint32_t)f2bf(a8[3]) << 16);
      wv.z = (uint32_t)f2bf(a8[4]) | ((uint32_t)f2bf(a8[5]) << 16);
      wv.w = (uint32_t)f2bf(a8[6]) | ((uint32_t)f2bf(a8[7]) << 16);
      *(uint4*)(aggr + row * 256 + ((c16 ^ (row & 7)) * 16)) = wv;
    }
  }

  __syncthreads();  // aggr visible to all waves

  // ---- GEMM: K=256 (kt 0-3 = x direct from global; kt 4-7 = aggr from LDS), B direct ----
  floatx4 acc[2][2];
#pragma unroll
  for (int mi = 0; mi < 2; ++mi)
#pragma unroll
    for (int ni = 0; ni < 2; ++ni) acc[mi][ni] = (floatx4){0.f, 0.f, 0.f, 0.f};

#pragma unroll
  for (int kt = 0; kt < 8; ++kt) {
    short8 a[2], b[2];
#pragma unroll
    for (int mi = 0; mi < 2; ++mi) {
      int row = mi * 16 + c16;  // A-frag: row = lane&15 (+16), k-half = q16
      if (kt < 4) {
        a[mi] = *(const short8*)(Xbb + (size_t)(tile + row) * 256 + kt * 64 + q16 * 16);
      } else {
        int slot = (((kt - 4) * 4 + q16) ^ (row & 7)) * 16;
        a[mi] = *(const short8*)(aggr + row * 256 + slot);
      }
    }
#pragma unroll
    for (int ni = 0; ni < 2; ++ni) {
      int o = w * 32 + ni * 16 + c16;  // B-frag: col = lane&15, k-half = q16 (L1/L2-hot)
      b[ni] = *(const short8*)(Btb + (size_t)o * 512 + kt * 64 + q16 * 16);
    }
    __builtin_amdgcn_s_setprio(1);
    acc[0][0] = __builtin_amdgcn_mfma_f32_16x16x32_bf16(a[0], b[0], acc[0][0], 0, 0, 0);
    acc[0][1] = __builtin_amdgcn_mfma_f32_16x16x32_bf16(a[0], b[1], acc[0][1], 0, 0, 0);
    acc[1][0] = __builtin_amdgcn_mfma_f32_16x16x32_bf16(a[1], b[0], acc[1][0], 0, 0, 0);
    acc[1][1] = __builtin_amdgcn_mfma_f32_16x16x32_bf16(a[1], b[1], acc[1][1], 0, 0, 0);
    __builtin_amdgcn_s_setprio(0);
  }

  // ---- epilogue: C/D layout col=lane&15, row=q16*4+reg (m89-verified); bias+relu ----
#pragma unroll
  for (int mi = 0; mi < 2; ++mi) {
    int rbase = tile + mi * 16 + q16 * 4;
#pragma unroll
    for (int r = 0; r < 4; ++r) {
      float* orow = out + (size_t)(rbase + r) * 128 + w * 32 + c16;
#pragma unroll
      for (int ni = 0; ni < 2; ++ni) {
        float vv = acc[mi][ni][r] + bcol[ni];
        orow[ni * 16] = vv > 0.f ? vv : 0.f;
      }
    }
  }
}

extern "C" void kernel_launch(void* const* d_in, const int* in_sizes, int n_in,
                              void* d_out, int out_size, void* d_ws, size_t ws_size,
                              hipStream_t stream) {
  const int* nbrs  = (const int*)d_in[0];
  const float* x   = (const float*)d_in[1];
  const float* W1  = (const float*)d_in[2];
  const float* b1  = (const float*)d_in[3];
  const float* W2  = (const float*)d_in[4];
  const float* b2  = (const float*)d_in[5];
  float* out = (float*)d_out;

  // ws layout: Xb bf16 [100000][128] | Bt bf16 [128][256] | bias f32 [128]
  unsigned short* Xb = (unsigned short*)d_ws;
  unsigned short* Bt = Xb + (size_t)N_NODES * 128;
  float* bias = (float*)(Bt + 128 * 256);

  k_convert<<<12628, 256, 0, stream>>>(x, Xb, W1, b1, W2, b2, Bt, bias);
  k_fused<<<3125, 256, 0, stream>>>(nbrs, Xb, Bt, bias, out);
}

// Round 6
// 170.577 us; speedup vs baseline: 1.2157x; 1.0427x over previous
//
#include <hip/hip_runtime.h>
#include <stdint.h>

// GraphConvolution: out = relu(x@W1^T + b1 + aggr@W2^T + b2), aggr = sum of 16 neighbor rows.
// R6: fused kernel, tile=32, 3125 blocks (R5 occupancy regime) with:
//  - software-pipelined gather (double-buffered node loads, >=2x MLP/wave; VGPR cap raised
//    to ~85 via __launch_bounds__(256,6) — R5's cap of 64 left compiler at 28 VGPR, ~2 loads
//    in flight, 3.1 TB/s latency-bound)
//  - x-tile staged via global_load_lds at kernel start (latency hidden under gather; replaces
//    50%-line-efficiency strided direct A-frag reads), XOR-swizzled source / linear LDS dest
//  - GEMM: A-frags from swizzled LDS (x + aggr), B direct from global (64KB L2-hot).

#define N_NODES 100000
#define DEG 16

typedef __attribute__((ext_vector_type(8))) short short8;
typedef __attribute__((ext_vector_type(4))) float floatx4;

static __device__ __forceinline__ unsigned short f2bf(float f) {
  union { float f; uint32_t u; } v; v.f = f;
  uint32_t u = v.u;
  return (unsigned short)((u + 0x7fffu + ((u >> 16) & 1u)) >> 16);  // RNE
}
static __device__ __forceinline__ float bf2f(uint32_t bits16) {
  union { uint32_t u; float f; } v; v.u = bits16 << 16; return v.f;
}

// ---- kernel 1: x fp32 -> bf16 Xb[100000][128]  +  W/bias prep (merged) ----
__global__ __launch_bounds__(256) void k_convert(const float* __restrict__ x,
                                                 unsigned short* __restrict__ Xb,
                                                 const float* __restrict__ W1, const float* __restrict__ b1,
                                                 const float* __restrict__ W2, const float* __restrict__ b2,
                                                 unsigned short* __restrict__ Bt, float* __restrict__ bias) {
  int b = blockIdx.x;
  if (b < 12500) {                      // 12500*256 threads == N*32 float4 chunks exactly
    int t = b * 256 + threadIdx.x;
    int n = t >> 5, c4 = t & 31;
    float4 v = *(const float4*)(x + (size_t)n * 128 + (size_t)c4 * 4);
    ushort4 o;
    o.x = f2bf(v.x); o.y = f2bf(v.y); o.z = f2bf(v.z); o.w = f2bf(v.w);
    *(ushort4*)(Xb + (size_t)n * 128 + (size_t)c4 * 4) = o;
  } else {                              // Bt row o = [W1[o,:], W2[o,:]] bf16; bias = b1+b2
    int t = (b - 12500) * 256 + threadIdx.x;  // 0..32767
    int o = t >> 8, k = t & 255;
    float v = (k < 128) ? W1[o * 128 + k] : W2[o * 128 + (k - 128)];
    Bt[t] = f2bf(v);
    if (t < 128) bias[t] = b1[t] + b2[t];
  }
}

// ---- kernel 2: fused gather + GEMM, tile = 32 rows, 4 waves ----
// LDS 16KB: xbuf [32 rows][16 slots x16B] + aggr [32][16], phys_slot = logical ^ (row&7).
// Wave w gathers nodes [tile+8w,+8); computes output cols [32w, 32w+32).
__global__ __launch_bounds__(256, 6) void k_fused(const int* __restrict__ nbrs,
                                                  const unsigned short* __restrict__ Xb,
                                                  const unsigned short* __restrict__ Bt,
                                                  const float* __restrict__ bias,
                                                  float* __restrict__ out) {
  __shared__ uint4 lds4[1024];  // 16KB
  char* xbuf = (char*)lds4;          // 8KB
  char* aggr = (char*)lds4 + 8192;   // 8KB
  const int tid = threadIdx.x;
  const int lane = tid & 63;
  const int w = tid >> 6;
  const int q16 = lane >> 4, c16 = lane & 15;
  const int tile = blockIdx.x * 32;   // 3125*32 = 100000 exactly
  const char* Xbb = (const char*)Xb;  // 256B rows
  const char* Btb = (const char*)Bt;  // 512B rows

  // ---- stage x-tile (8KB) via gload_lds; source pre-swizzled, LDS dest linear ----
  // instr g covers rows 4g..4g+3; lane l -> row 4g+(l>>4), phys slot l&15; source reads
  // logical slot (l&15)^(row&7) so that read-side phys = logical^(row&7).
#pragma unroll
  for (int i = 0; i < 2; ++i) {
    int g = w * 2 + i;
    int row = 4 * g + (lane >> 4);
    const char* src = Xbb + (size_t)(tile + row) * 256 + ((size_t)((lane & 15) ^ (row & 7))) * 16;
    __builtin_amdgcn_global_load_lds((const __attribute__((address_space(1))) uint32_t*)src,
                                     (__attribute__((address_space(3))) uint32_t*)(xbuf + g * 1024),
                                     16, 0, 0);
  }

  float bcol[2];
#pragma unroll
  for (int ni = 0; ni < 2; ++ni) bcol[ni] = bias[w * 32 + ni * 16 + c16];

  // this wave's 8 nodes' neighbour lists (128 ints, coalesced)
  int base = (tile + w * 8) * DEG;
  int midx0 = nbrs[base + lane];        // nodes q=0..3: index j of node q at lane (q&3)*16+j
  int midx1 = nbrs[base + 64 + lane];   // nodes q=4..7

  // ---- software-pipelined gather: ISSUE(q+1) in flight while CONSUME(q) reduces ----
  uint4 pA[4], pB[4];
  auto ISSUE = [&](int q, uint4* buf) {
    int midx = (q < 4) ? midx0 : midx1;
    int flat = (q & 3) * 16 + q16;
#pragma unroll
    for (int i = 0; i < 4; ++i) {
      int nb = __shfl(midx, flat + i * 4);
      buf[i] = *(const uint4*)(Xbb + (size_t)nb * 256 + c16 * 16);
    }
  };
  auto CONSUME = [&](int q, uint4* buf) {
    float a8[8] = {0.f, 0.f, 0.f, 0.f, 0.f, 0.f, 0.f, 0.f};
#pragma unroll
    for (int i = 0; i < 4; ++i) {
      uint4 pv = buf[i];
      a8[0] += bf2f(pv.x & 0xffffu); a8[1] += bf2f(pv.x >> 16);
      a8[2] += bf2f(pv.y & 0xffffu); a8[3] += bf2f(pv.y >> 16);
      a8[4] += bf2f(pv.z & 0xffffu); a8[5] += bf2f(pv.z >> 16);
      a8[6] += bf2f(pv.w & 0xffffu); a8[7] += bf2f(pv.w >> 16);
    }
#pragma unroll
    for (int k = 0; k < 8; ++k) {
      a8[k] += __shfl_xor(a8[k], 16);
      a8[k] += __shfl_xor(a8[k], 32);
    }
    if (lane < 16) {
      int row = w * 8 + q;
      uint4 wv;
      wv.x = (uint32_t)f2bf(a8[0]) | ((uint32_t)f2bf(a8[1]) << 16);
      wv.y = (uint32_t)f2bf(a8[2]) | ((uint32_t)f2bf(a8[3]) << 16);
      wv.z = (uint32_t)f2bf(a8[4]) | ((uint32_t)f2bf(a8[5]) << 16);
      wv.w = (uint32_t)f2bf(a8[6]) | ((uint32_t)f2bf(a8[7]) << 16);
      *(uint4*)(aggr + row * 256 + ((c16 ^ (row & 7)) * 16)) = wv;
    }
  };

  ISSUE(0, pA);
  ISSUE(1, pB); CONSUME(0, pA);
  ISSUE(2, pA); CONSUME(1, pB);
  ISSUE(3, pB); CONSUME(2, pA);
  ISSUE(4, pA); CONSUME(3, pB);
  ISSUE(5, pB); CONSUME(4, pA);
  ISSUE(6, pA); CONSUME(5, pB);
  ISSUE(7, pB); CONSUME(6, pA);
  CONSUME(7, pB);

  __syncthreads();  // aggr + staged xbuf visible (compiler drains vmcnt/lgkmcnt)

  // ---- GEMM: K=256; kt 0-3 from xbuf, kt 4-7 from aggr (same swizzle); B direct ----
  floatx4 acc[2][2];
#pragma unroll
  for (int mi = 0; mi < 2; ++mi)
#pragma unroll
    for (int ni = 0; ni < 2; ++ni) acc[mi][ni] = (floatx4){0.f, 0.f, 0.f, 0.f};

#pragma unroll
  for (int kt = 0; kt < 8; ++kt) {
    const char* srcb = (kt < 4) ? xbuf : aggr;
    int s = (kt & 3) * 4 + q16;  // logical 16B slot
    short8 a[2], b[2];
#pragma unroll
    for (int mi = 0; mi < 2; ++mi) {
      int row = mi * 16 + c16;
      a[mi] = *(const short8*)(srcb + row * 256 + ((s ^ (row & 7)) * 16));
    }
#pragma unroll
    for (int ni = 0; ni < 2; ++ni) {
      int o = w * 32 + ni * 16 + c16;
      b[ni] = *(const short8*)(Btb + (size_t)o * 512 + kt * 64 + q16 * 16);
    }
    __builtin_amdgcn_s_setprio(1);
    acc[0][0] = __builtin_amdgcn_mfma_f32_16x16x32_bf16(a[0], b[0], acc[0][0], 0, 0, 0);
    acc[0][1] = __builtin_amdgcn_mfma_f32_16x16x32_bf16(a[0], b[1], acc[0][1], 0, 0, 0);
    acc[1][0] = __builtin_amdgcn_mfma_f32_16x16x32_bf16(a[1], b[0], acc[1][0], 0, 0, 0);
    acc[1][1] = __builtin_amdgcn_mfma_f32_16x16x32_bf16(a[1], b[1], acc[1][1], 0, 0, 0);
    __builtin_amdgcn_s_setprio(0);
  }

  // ---- epilogue: C/D layout col=lane&15, row=q16*4+reg (m89-verified); bias+relu ----
#pragma unroll
  for (int mi = 0; mi < 2; ++mi) {
    int rbase = tile + mi * 16 + q16 * 4;
#pragma unroll
    for (int r = 0; r < 4; ++r) {
      float* orow = out + (size_t)(rbase + r) * 128 + w * 32 + c16;
#pragma unroll
      for (int ni = 0; ni < 2; ++ni) {
        float vv = acc[mi][ni][r] + bcol[ni];
        orow[ni * 16] = vv > 0.f ? vv : 0.f;
      }
    }
  }
}

extern "C" void kernel_launch(void* const* d_in, const int* in_sizes, int n_in,
                              void* d_out, int out_size, void* d_ws, size_t ws_size,
                              hipStream_t stream) {
  const int* nbrs  = (const int*)d_in[0];
  const float* x   = (const float*)d_in[1];
  const float* W1  = (const float*)d_in[2];
  const float* b1  = (const float*)d_in[3];
  const float* W2  = (const float*)d_in[4];
  const float* b2  = (const float*)d_in[5];
  float* out = (float*)d_out;

  // ws layout: Xb bf16 [100000][128] | Bt bf16 [128][256] | bias f32 [128]
  unsigned short* Xb = (unsigned short*)d_ws;
  unsigned short* Bt = Xb + (size_t)N_NODES * 128;
  float* bias = (float*)(Bt + 128 * 256);

  k_convert<<<12628, 256, 0, stream>>>(x, Xb, W1, b1, W2, b2, Bt, bias);
  k_fused<<<3125, 256, 0, stream>>>(nbrs, Xb, Bt, bias, out);
}